// Round 3
// baseline (41.273 us; speedup 1.0000x reference)
//
#include <hip/hip_runtime.h>
#include <math.h>

#define N_ANCH 87296
#define NCLS 91
#define NBINS 4096
#define K_CAND 256
#define CAP 512
#define MAX_OUT 100
#define IOU_TH 0.6f

// ws layout (bytes):
//      0: hist       (NBINS*4 = 16384)
//  16384: counter    (4)
//  16388: found_bin  (4)
//  16400: cand_score (CAP*4  = 2048)
//  18448: cand_box   (CAP*16 = 8192)   (18448 % 16 == 0)
//  26640: cand_label (CAP*4  = 2048)
//  28688: scores_all (N_ANCH*4 = 349184)

__device__ __forceinline__ float sigmoidf_(float x) {
    return 1.0f / (1.0f + expf(-x));
}

// Kernel A: per-anchor score + histogram. Wave-cooperative LDS staging:
// each wave float4-loads its 64 contiguous rows (23296 B) coalesced into LDS,
// then each lane max-reduces its own row from LDS (dword stride 91 is odd ->
// lanes l,l+32 alias one bank = free 2-way conflict).
__global__ void score_kernel(const float* __restrict__ logits,
                             const float* __restrict__ ctr,
                             float* __restrict__ scores,
                             unsigned* __restrict__ hist) {
    __shared__ float lds[2 * 64 * 91];   // 46592 B, 2 waves
    const int tid  = threadIdx.x;
    const int lane = tid & 63;
    const int w    = tid >> 6;
    const int rowbase = blockIdx.x * 128 + w * 64;

    // stage: 64 rows * 91 floats = 5824 floats = 1456 float4 (16B-aligned:
    // rowbase is a multiple of 64, 64*91*4 = 23296 B ≡ 0 mod 16)
    const float4* g4 = (const float4*)logits + (size_t)rowbase * 91 / 4;
    float4* l4 = (float4*)(lds + w * 5824);
    #pragma unroll
    for (int k = 0; k < 23; ++k) {
        int idx = k * 64 + lane;
        if (idx < 1456) l4[idx] = g4[idx];
    }
    __syncthreads();

    const int i = rowbase + lane;
    const float* row = lds + w * 5824 + lane * 91;
    float m = row[0];
    #pragma unroll
    for (int j = 1; j < NCLS; ++j) m = fmaxf(m, row[j]);
    float s = sqrtf(sigmoidf_(m) * sigmoidf_(ctr[i]));
    scores[i] = s;
    int b = (int)(s * (float)NBINS);
    b = min(max(b, 0), NBINS - 1);
    atomicAdd(&hist[b], 1u);
}

// Kernel B: single-wave fully-parallel threshold find.
// lane l owns bins [l*64, l*64+64) in 16 uint4 registers; per-lane sum;
// 6-step shfl_down suffix scan gives suf[l] = #scores with bin >= l*64;
// ballot+clz finds the crossing lane; that lane refines in-register.
__global__ void thresh_kernel(const unsigned* __restrict__ hist,
                              int* __restrict__ found_bin) {
    const int lane = threadIdx.x;
    const uint4* h4 = (const uint4*)hist;       // 1024 uint4
    uint4 c[16];
    #pragma unroll
    for (int q = 0; q < 16; ++q) c[q] = h4[lane * 16 + q];

    unsigned local = 0;
    #pragma unroll
    for (int q = 0; q < 16; ++q) local += c[q].x + c[q].y + c[q].z + c[q].w;

    unsigned p = local;                          // suffix-inclusive scan
    #pragma unroll
    for (int d = 1; d < 64; d <<= 1) {
        unsigned t = (unsigned)__shfl_down((int)p, d, 64);
        if (lane + d < 64) p += t;
    }
    unsigned long long mask = __ballot(p >= K_CAND);
    int L = 63 - __clzll(mask);                  // mask != 0 since N >= K
    unsigned sufAbove = (unsigned)__shfl((int)p, L + 1, 64);
    if (L == 63) sufAbove = 0u;

    if (lane == L) {
        unsigned cum = sufAbove;
        int fb = L * 64;
        bool found = false;
        #pragma unroll
        for (int q = 15; q >= 0; --q) {          // descending bins: w,z,y,x
            cum += c[q].w; if (!found && cum >= K_CAND) { fb = L * 64 + q * 4 + 3; found = true; }
            cum += c[q].z; if (!found && cum >= K_CAND) { fb = L * 64 + q * 4 + 2; found = true; }
            cum += c[q].y; if (!found && cum >= K_CAND) { fb = L * 64 + q * 4 + 1; found = true; }
            cum += c[q].x; if (!found && cum >= K_CAND) { fb = L * 64 + q * 4 + 0; found = true; }
        }
        *found_bin = fb;
    }
}

// Kernel C: compact candidates >= threshold bin; recompute label + decode box
__global__ void compact_kernel(const float* __restrict__ logits,
                               const float* __restrict__ boxreg,
                               const float* __restrict__ anchors,
                               const float* __restrict__ scores,
                               const int* __restrict__ found_bin,
                               unsigned* __restrict__ counter,
                               float* __restrict__ cscore,
                               float4* __restrict__ cbox,
                               int* __restrict__ clabel) {
    int i = blockIdx.x * blockDim.x + threadIdx.x;
    if (i >= N_ANCH) return;
    float s = scores[i];
    int b = (int)(s * (float)NBINS);
    b = min(max(b, 0), NBINS - 1);
    if (b < *found_bin) return;
    unsigned pos = atomicAdd(counter, 1u);
    if (pos >= CAP) return;

    const float* row = logits + (long)i * NCLS;
    float m = row[0];
    int lab = 0;
    #pragma unroll
    for (int j = 1; j < NCLS; ++j) {
        float v = row[j];
        if (v > m) { m = v; lab = j; }
    }

    float a0 = anchors[i * 4 + 0], a1 = anchors[i * 4 + 1];
    float a2 = anchors[i * 4 + 2], a3 = anchors[i * 4 + 3];
    float cx = 0.5f * (a0 + a2);
    float cy = 0.5f * (a1 + a3);
    float w  = a2 - a0;
    float h  = a3 - a1;
    float r0 = boxreg[i * 4 + 0], r1 = boxreg[i * 4 + 1];
    float r2 = boxreg[i * 4 + 2], r3 = boxreg[i * 4 + 3];
    float4 bb;
    bb.x = cx - r0 * w;
    bb.y = cy - r1 * h;
    bb.z = cx + r2 * w;
    bb.w = cy + r3 * h;

    cscore[pos] = s;
    cbox[pos]   = bb;
    clabel[pos] = lab;
}

// Kernel D: greedy NMS, one candidate per thread (512 threads = 8 waves).
// Zero-area winner => reference "locks" (0/0=NaN suppresses nothing incl.
// itself) => fill remaining outputs, exit.
__global__ void nms_kernel(const unsigned* __restrict__ counter,
                           const float* __restrict__ cscore,
                           const float4* __restrict__ cbox,
                           const int* __restrict__ clabel,
                           float* __restrict__ out) {
    __shared__ float s_best[8];
    __shared__ int   s_bid[8];
    __shared__ float s_box[5];   // x1,y1,x2,y2,area
    __shared__ int   s_lab;

    const int tid  = threadIdx.x;
    const int lane = tid & 63;
    const int wid  = tid >> 6;
    int M = (int)min(*counter, (unsigned)CAP);

    float sc, X1, Y1, X2, Y2, AR;
    int LAB;
    if (tid < M) {
        sc = cscore[tid];
        float4 b = cbox[tid];
        X1 = b.x; Y1 = b.y; X2 = b.z; Y2 = b.w;
        AR = fmaxf(b.z - b.x, 0.0f) * fmaxf(b.w - b.y, 0.0f);
        LAB = clabel[tid];
    } else {
        sc = -INFINITY;
        X1 = Y1 = X2 = Y2 = AR = 0.0f;
        LAB = 0;
    }

    for (int it = 0; it < MAX_OUT; ++it) {
        float b = sc;
        int id = tid;
        #pragma unroll
        for (int d = 32; d >= 1; d >>= 1) {
            float ob = __shfl_xor(b, d, 64);
            int   oid = __shfl_xor(id, d, 64);
            if (ob > b) { b = ob; id = oid; }
        }
        if (lane == 0) { s_best[wid] = b; s_bid[wid] = id; }
        __syncthreads();
        float gb = s_best[0];
        int gid = s_bid[0];
        #pragma unroll
        for (int w = 1; w < 8; ++w) {
            if (s_best[w] > gb) { gb = s_best[w]; gid = s_bid[w]; }
        }
        if (tid == gid) {
            s_box[0] = X1; s_box[1] = Y1; s_box[2] = X2; s_box[3] = Y2;
            s_box[4] = AR; s_lab = LAB;
        }
        __syncthreads();
        float sx1 = s_box[0], sy1 = s_box[1], sx2 = s_box[2], sy2 = s_box[3];
        float sar = s_box[4];
        int   slab = s_lab;

        if (tid == 0) {
            out[it * 4 + 0] = sx1;
            out[it * 4 + 1] = sy1;
            out[it * 4 + 2] = sx2;
            out[it * 4 + 3] = sy2;
            out[4 * MAX_OUT + it] = (float)slab;
            out[5 * MAX_OUT + it] = gb;
        }

        // Lock: zero-area winner has inter==0 with every box, iou = 0/0 = NaN
        // for itself, NaN > 0.6 false -> nothing suppressed -> reference
        // re-selects the same box for every remaining slot.
        if (sar == 0.0f) {
            for (int r = it + 1 + tid; r < MAX_OUT; r += (int)blockDim.x) {
                out[r * 4 + 0] = sx1;
                out[r * 4 + 1] = sy1;
                out[r * 4 + 2] = sx2;
                out[r * 4 + 3] = sy2;
                out[4 * MAX_OUT + r] = (float)slab;
                out[5 * MAX_OUT + r] = gb;
            }
            return;
        }

        float ix1 = fmaxf(sx1, X1);
        float iy1 = fmaxf(sy1, Y1);
        float ix2 = fminf(sx2, X2);
        float iy2 = fminf(sy2, Y2);
        float inter = fmaxf(ix2 - ix1, 0.0f) * fmaxf(iy2 - iy1, 0.0f);
        float iou = inter / (sar + AR - inter);
        if (iou > IOU_TH) sc = -INFINITY;
        __syncthreads();
    }
}

extern "C" void kernel_launch(void* const* d_in, const int* in_sizes, int n_in,
                              void* d_out, int out_size, void* d_ws, size_t ws_size,
                              hipStream_t stream) {
    const float* logits  = (const float*)d_in[0];
    const float* boxreg  = (const float*)d_in[1];
    const float* ctr     = (const float*)d_in[2];
    const float* anchors = (const float*)d_in[3];
    float* out = (float*)d_out;

    char* ws = (char*)d_ws;
    unsigned* hist    = (unsigned*)(ws + 0);
    unsigned* counter = (unsigned*)(ws + 16384);
    int* found_bin    = (int*)(ws + 16388);
    float* cscore     = (float*)(ws + 16400);
    float4* cbox      = (float4*)(ws + 18448);
    int* clabel       = (int*)(ws + 26640);
    float* scores     = (float*)(ws + 28688);

    hipMemsetAsync(ws, 0, 16392, stream);

    score_kernel<<<N_ANCH / 128, 128, 0, stream>>>(logits, ctr, scores, hist);
    thresh_kernel<<<1, 64, 0, stream>>>(hist, found_bin);
    compact_kernel<<<(N_ANCH + 255) / 256, 256, 0, stream>>>(logits, boxreg, anchors, scores,
                                                             found_bin, counter, cscore, cbox, clabel);
    nms_kernel<<<1, 512, 0, stream>>>(counter, cscore, cbox, clabel, out);
}

// Round 4
// 34.204 us; speedup vs baseline: 1.2067x; 1.2067x over previous
//
#include <hip/hip_runtime.h>
#include <math.h>

#define N_ANCH 87296
#define NCLS 91
#define NBINS 4096
#define K_CAND 256
#define CAP 512
#define MAX_OUT 100
#define IOU_TH 0.6f
#define T2 1024          // threads in fused kernel (16 waves)

// ws layout: scores_all at offset 0 (N_ANCH*4 bytes, 16B-aligned)

__device__ __forceinline__ float sigmoidf_(float x) {
    return 1.0f / (1.0f + expf(-x));
}

// Kernel A: per-anchor score. Wave-cooperative LDS staging: each wave
// float4-loads its 64 contiguous rows (23296 B) coalesced into LDS, then each
// lane max-reduces its own row (dword stride 91 is odd -> free 2-way bank
// aliasing for lanes l, l+32).
__global__ void score_kernel(const float* __restrict__ logits,
                             const float* __restrict__ ctr,
                             float* __restrict__ scores) {
    __shared__ float lds[2 * 64 * 91];   // 46592 B, 2 waves
    const int tid  = threadIdx.x;
    const int lane = tid & 63;
    const int w    = tid >> 6;
    const int rowbase = blockIdx.x * 128 + w * 64;

    const float4* g4 = (const float4*)logits + (size_t)rowbase * 91 / 4;
    float4* l4 = (float4*)(lds + w * 5824);
    #pragma unroll
    for (int k = 0; k < 23; ++k) {
        int idx = k * 64 + lane;
        if (idx < 1456) l4[idx] = g4[idx];
    }
    __syncthreads();

    const int i = rowbase + lane;
    const float* row = lds + w * 5824 + lane * 91;
    float m = row[0];
    #pragma unroll
    for (int j = 1; j < NCLS; ++j) m = fmaxf(m, row[j]);
    scores[i] = sqrtf(sigmoidf_(m) * sigmoidf_(ctr[i]));
}

// Kernel B (fused): single WG, 16 waves. LDS histogram -> threshold bin ->
// compact candidates -> per-thread decode -> register-resident greedy NMS
// with zero-area lock shortcut (bit-exact vs reference's 0/0=NaN semantics).
__global__ void __launch_bounds__(T2)
select_nms_kernel(const float* __restrict__ scores,
                  const float* __restrict__ logits,
                  const float* __restrict__ boxreg,
                  const float* __restrict__ anchors,
                  float* __restrict__ out) {
    __shared__ unsigned hist[NBINS];     // 16 KB
    __shared__ float    cs[CAP];
    __shared__ int      cidx[CAP];
    __shared__ unsigned cnt;
    __shared__ int      fbin;
    __shared__ float    s_best[16];
    __shared__ int      s_bid[16];
    __shared__ float    s_box[5];        // x1,y1,x2,y2,area
    __shared__ int      s_lab;

    const int tid  = threadIdx.x;
    const int lane = tid & 63;
    const int wid  = tid >> 6;

    for (int b = tid; b < NBINS; b += T2) hist[b] = 0u;
    if (tid == 0) cnt = 0u;
    __syncthreads();

    // ---- pass 1: histogram (float4 over scores) ----
    const float4* s4 = (const float4*)scores;       // 21824 float4
    #pragma unroll
    for (int k = 0; k < 22; ++k) {
        int idx = k * T2 + tid;
        if (idx < N_ANCH / 4) {
            float4 v = s4[idx];
            int b0 = min(max((int)(v.x * (float)NBINS), 0), NBINS - 1);
            int b1 = min(max((int)(v.y * (float)NBINS), 0), NBINS - 1);
            int b2 = min(max((int)(v.z * (float)NBINS), 0), NBINS - 1);
            int b3 = min(max((int)(v.w * (float)NBINS), 0), NBINS - 1);
            atomicAdd(&hist[b0], 1u);
            atomicAdd(&hist[b1], 1u);
            atomicAdd(&hist[b2], 1u);
            atomicAdd(&hist[b3], 1u);
        }
    }
    __syncthreads();

    // ---- threshold find: wave 0 only (verified suffix-scan logic) ----
    if (tid < 64) {
        const uint4* h4 = (const uint4*)hist;       // 1024 uint4
        uint4 c[16];
        #pragma unroll
        for (int q = 0; q < 16; ++q) c[q] = h4[lane * 16 + q];

        unsigned local = 0;
        #pragma unroll
        for (int q = 0; q < 16; ++q) local += c[q].x + c[q].y + c[q].z + c[q].w;

        unsigned p = local;                          // suffix-inclusive scan
        #pragma unroll
        for (int d = 1; d < 64; d <<= 1) {
            unsigned t = (unsigned)__shfl_down((int)p, d, 64);
            if (lane + d < 64) p += t;
        }
        unsigned long long mask = __ballot(p >= K_CAND);
        int L = 63 - __clzll(mask);
        unsigned sufAbove = (unsigned)__shfl((int)p, L + 1, 64);
        if (L == 63) sufAbove = 0u;

        if (lane == L) {
            unsigned cum = sufAbove;
            int fb = L * 64;
            bool found = false;
            #pragma unroll
            for (int q = 15; q >= 0; --q) {          // descending bins
                cum += c[q].w; if (!found && cum >= K_CAND) { fb = L * 64 + q * 4 + 3; found = true; }
                cum += c[q].z; if (!found && cum >= K_CAND) { fb = L * 64 + q * 4 + 2; found = true; }
                cum += c[q].y; if (!found && cum >= K_CAND) { fb = L * 64 + q * 4 + 1; found = true; }
                cum += c[q].x; if (!found && cum >= K_CAND) { fb = L * 64 + q * 4 + 0; found = true; }
            }
            fbin = fb;
        }
    }
    __syncthreads();
    const int FB = fbin;

    // ---- pass 2: compact candidates >= FB ----
    #pragma unroll
    for (int k = 0; k < 22; ++k) {
        int idx = k * T2 + tid;
        if (idx < N_ANCH / 4) {
            float4 v = s4[idx];
            float vv[4] = {v.x, v.y, v.z, v.w};
            #pragma unroll
            for (int c = 0; c < 4; ++c) {
                float s = vv[c];
                int b = min(max((int)(s * (float)NBINS), 0), NBINS - 1);
                if (b >= FB) {
                    unsigned pos = atomicAdd(&cnt, 1u);
                    if (pos < CAP) { cs[pos] = s; cidx[pos] = idx * 4 + c; }
                }
            }
        }
    }
    __syncthreads();
    const int M = (int)min(cnt, (unsigned)CAP);

    // ---- decode: thread t < M owns candidate t in registers ----
    float SC, X1, Y1, X2, Y2, AR;
    int LAB;
    if (tid < M) {
        int i = cidx[tid];
        SC = cs[tid];
        const float* row = logits + (long)i * NCLS;
        float m = row[0];
        int lab = 0;
        #pragma unroll
        for (int j = 1; j < NCLS; ++j) {
            float v = row[j];
            if (v > m) { m = v; lab = j; }
        }
        LAB = lab;
        float a0 = anchors[i * 4 + 0], a1 = anchors[i * 4 + 1];
        float a2 = anchors[i * 4 + 2], a3 = anchors[i * 4 + 3];
        float cx = 0.5f * (a0 + a2);
        float cy = 0.5f * (a1 + a3);
        float w  = a2 - a0;
        float h  = a3 - a1;
        float r0 = boxreg[i * 4 + 0], r1 = boxreg[i * 4 + 1];
        float r2 = boxreg[i * 4 + 2], r3 = boxreg[i * 4 + 3];
        X1 = cx - r0 * w;
        Y1 = cy - r1 * h;
        X2 = cx + r2 * w;
        Y2 = cy + r3 * h;
        AR = fmaxf(X2 - X1, 0.0f) * fmaxf(Y2 - Y1, 0.0f);
    } else {
        SC = -INFINITY;
        X1 = Y1 = X2 = Y2 = AR = 0.0f;
        LAB = 0;
    }
    __syncthreads();

    // ---- greedy NMS ----
    for (int it = 0; it < MAX_OUT; ++it) {
        float b = SC;
        int id = tid;
        #pragma unroll
        for (int d = 32; d >= 1; d >>= 1) {
            float ob = __shfl_xor(b, d, 64);
            int   oid = __shfl_xor(id, d, 64);
            if (ob > b) { b = ob; id = oid; }
        }
        if (lane == 0) { s_best[wid] = b; s_bid[wid] = id; }
        __syncthreads();
        float gb = s_best[0];
        int gid = s_bid[0];
        #pragma unroll
        for (int w = 1; w < 16; ++w) {
            if (s_best[w] > gb) { gb = s_best[w]; gid = s_bid[w]; }
        }
        if (tid == gid) {
            s_box[0] = X1; s_box[1] = Y1; s_box[2] = X2; s_box[3] = Y2;
            s_box[4] = AR; s_lab = LAB;
        }
        __syncthreads();
        float sx1 = s_box[0], sy1 = s_box[1], sx2 = s_box[2], sy2 = s_box[3];
        float sar = s_box[4];
        int   slab = s_lab;

        if (tid == 0) {
            out[it * 4 + 0] = sx1;
            out[it * 4 + 1] = sy1;
            out[it * 4 + 2] = sx2;
            out[it * 4 + 3] = sy2;
            out[4 * MAX_OUT + it] = (float)slab;
            out[5 * MAX_OUT + it] = gb;
        }

        // Lock: zero-area winner -> inter==0 with every box, iou=0/0=NaN for
        // itself, NaN>0.6 false -> nothing suppressed -> reference re-selects
        // this same box for every remaining slot.
        if (sar == 0.0f) {
            for (int r = it + 1 + tid; r < MAX_OUT; r += T2) {
                out[r * 4 + 0] = sx1;
                out[r * 4 + 1] = sy1;
                out[r * 4 + 2] = sx2;
                out[r * 4 + 3] = sy2;
                out[4 * MAX_OUT + r] = (float)slab;
                out[5 * MAX_OUT + r] = gb;
            }
            return;
        }

        float ix1 = fmaxf(sx1, X1);
        float iy1 = fmaxf(sy1, Y1);
        float ix2 = fminf(sx2, X2);
        float iy2 = fminf(sy2, Y2);
        float inter = fmaxf(ix2 - ix1, 0.0f) * fmaxf(iy2 - iy1, 0.0f);
        float iou = inter / (sar + AR - inter);
        if (iou > IOU_TH) SC = -INFINITY;
        __syncthreads();
    }
}

extern "C" void kernel_launch(void* const* d_in, const int* in_sizes, int n_in,
                              void* d_out, int out_size, void* d_ws, size_t ws_size,
                              hipStream_t stream) {
    const float* logits  = (const float*)d_in[0];
    const float* boxreg  = (const float*)d_in[1];
    const float* ctr     = (const float*)d_in[2];
    const float* anchors = (const float*)d_in[3];
    float* out = (float*)d_out;
    float* scores = (float*)d_ws;

    score_kernel<<<N_ANCH / 128, 128, 0, stream>>>(logits, ctr, scores);
    select_nms_kernel<<<1, T2, 0, stream>>>(scores, logits, boxreg, anchors, out);
}